// Round 10
// baseline (294.321 us; speedup 1.0000x reference)
//
#include <hip/hip_runtime.h>

#define SCALE 0.125f

constexpr int L_ = 1024, T_ = 1024, D_ = 64, HB_ = 64, QB = 16;

using f32x4  = __attribute__((ext_vector_type(4))) float;
using half8  = __attribute__((ext_vector_type(8))) _Float16;
using half4  = __attribute__((ext_vector_type(4))) _Float16;
using half2v = __attribute__((ext_vector_type(2))) _Float16;

#define BARRIER() asm volatile("s_waitcnt lgkmcnt(0)\n\ts_barrier" ::: "memory")

// ===========================================================================
// Prologue 1: K f32 -> Kh f16, same [hb][t][d] layout.
// ===========================================================================
__global__ __launch_bounds__(256) void cvt_k(const float* __restrict__ k,
                                             _Float16* __restrict__ kh) {
  const size_t i = ((size_t)blockIdx.x * 256 + threadIdx.x) * 8;
  f32x4 a = *(const f32x4*)(k + i);
  f32x4 b = *(const f32x4*)(k + i + 4);
  half8 h;
#pragma unroll
  for (int e = 0; e < 4; ++e) {
    h[e] = (_Float16)a[e];
    h[4 + e] = (_Float16)b[e];
  }
  *(half8*)(kh + i) = h;
}

// ===========================================================================
// Prologue 2: V f32 [hb][t][d] -> Vh f16 transposed [hb][d][t] (LDS transpose)
// ===========================================================================
__global__ __launch_bounds__(256) void cvt_v(const float* __restrict__ v,
                                             _Float16* __restrict__ vh) {
  __shared__ _Float16 ts[64][136];
  const int tid = threadIdx.x;
  const int hb = blockIdx.y;
  const int t0 = blockIdx.x * 128;

  // load rows: thread -> t-row t0 + (tid>>1), d = (tid&1)*32 .. +31
  {
    const int tr = tid >> 1, dh = (tid & 1) * 32;
    const float* p = v + ((size_t)hb * T_ + t0 + tr) * D_ + dh;
#pragma unroll
    for (int i = 0; i < 8; ++i) {
      f32x4 r = *(const f32x4*)(p + i * 4);
#pragma unroll
      for (int e = 0; e < 4; ++e) ts[dh + i * 4 + e][tr] = (_Float16)r[e];
    }
  }
  __syncthreads();
  // store rows: thread -> d = tid>>2, t quarter (tid&3)*32 .. +31
  {
    const int d = tid >> 2, tq = (tid & 3) * 32;
    _Float16* qo = vh + ((size_t)hb * D_ + d) * T_ + t0 + tq;
#pragma unroll
    for (int i = 0; i < 4; ++i)
      *(half8*)(qo + i * 8) = *(const half8*)&ts[d][tq + i * 8];
  }
}

// ===========================================================================
// Main kernel: barrier-free streaming main loop.
// One block = 16 q-rows x full T. Wave w owns t-subtile w*16..+15 per 64-t
// chunk. K/V frags load directly from f16 global (L2/L3-hot); prev is the
// only HBM stream, batched depth-4/8 in registers. E -> LDS (att phase),
// PV from registers (zero-padded K-slots, r8-validated). One barrier total.
// ===========================================================================
__global__ __launch_bounds__(256, 3) void attn_stream(
    const float* __restrict__ q, const _Float16* __restrict__ Kh,
    const _Float16* __restrict__ Vh, const float* __restrict__ prev,
    float* __restrict__ out, float* __restrict__ att) {
  __shared__ __align__(16) _Float16 El[QB][1032];  // 33024 B unnormalized E
  __shared__ __align__(16) float ob4[4][QB][68];   // 17408 B O partials
  __shared__ float zb[4][QB];

  const int ltile = blockIdx.x;   // 0..63
  const int hb    = blockIdx.y;   // 0..63
  const int tid = threadIdx.x;
  const int w = tid >> 6, l = tid & 63, l15 = l & 15, lg = l >> 4;
  const int qrow = ltile * QB + l15;

  // Q B-frag (swapped QK^T): lane holds Q[qrow][f*32 + lg*8 + e]
  half8 qb2[2];
  {
    const float* qp = q + ((size_t)hb * L_ + qrow) * D_ + lg * 8;
#pragma unroll
    for (int f = 0; f < 2; ++f)
#pragma unroll
      for (int e = 0; e < 8; ++e) qb2[f][e] = (_Float16)qp[f * 32 + e];
  }

  const float* prow =
      prev + ((size_t)hb * L_ + qrow) * (size_t)T_ + w * 16 + lg * 4;
  const _Float16* kb = Kh + (size_t)hb * T_ * D_;   // [t][d] f16
  const _Float16* vb = Vh + (size_t)hb * D_ * T_;   // [d][t] f16

  // prev register batching: two sets of 4 chunks (depth 4-8)
  f32x4 pcur[4], pnext[4];
#pragma unroll
  for (int j = 0; j < 4; ++j) pcur[j] = *(const f32x4*)(prow + j * 64);
#pragma unroll
  for (int j = 0; j < 4; ++j) pnext[j] = *(const f32x4*)(prow + (4 + j) * 64);

  float zsum = 0.f;
  f32x4 oacc[4];
#pragma unroll
  for (int nd = 0; nd < 4; ++nd) oacc[nd] = (f32x4){0.f, 0.f, 0.f, 0.f};

#pragma unroll
  for (int g = 0; g < 4; ++g) {
#pragma unroll
    for (int j = 0; j < 4; ++j) {
      const int c = g * 4 + j;
      const f32x4 pv = pcur[j];

      // QK^T (swapped): A-frag = Kh row, direct 16B global loads (cache-hot)
      const int trow = c * 64 + w * 16 + l15;
      half8 ka0 = *(const half8*)(kb + (size_t)trow * D_ + lg * 8);
      half8 ka1 = *(const half8*)(kb + (size_t)trow * D_ + 32 + lg * 8);
      f32x4 acc = {0.f, 0.f, 0.f, 0.f};
      acc = __builtin_amdgcn_mfma_f32_16x16x32_f16(ka0, qb2[0], acc, 0, 0, 0);
      acc = __builtin_amdgcn_mfma_f32_16x16x32_f16(ka1, qb2[1], acc, 0, 0, 0);

      // acc[i] = S^T[t = c*64 + w*16 + lg*4 + i][q = qrow]
      float e0 = __expf(acc[0] * SCALE + pv[0]);
      float e1 = __expf(acc[1] * SCALE + pv[1]);
      float e2 = __expf(acc[2] * SCALE + pv[2]);
      float e3 = __expf(acc[3] * SCALE + pv[3]);
      zsum += (e0 + e1) + (e2 + e3);
      half4 ev;
      ev[0] = (_Float16)e0; ev[1] = (_Float16)e1;
      ev[2] = (_Float16)e2; ev[3] = (_Float16)e3;
      *(half4*)&El[l15][c * 64 + w * 16 + lg * 4] = ev;  // att phase only

      // PV from registers: A k-slot lg*8+i := E[t=...lg*4+i], rest zero.
      // B-frag = Vh rows, direct 8B global loads (cache-hot).
      half8 af;
      af[0] = ev[0]; af[1] = ev[1]; af[2] = ev[2]; af[3] = ev[3];
      af[4] = af[5] = af[6] = af[7] = (_Float16)0.f;
#pragma unroll
      for (int nd = 0; nd < 4; ++nd) {
        half4 v4 = *(const half4*)(vb + (size_t)(nd * 16 + l15) * T_ +
                                   c * 64 + w * 16 + lg * 4);
        half8 vfb;
        vfb[0] = v4[0]; vfb[1] = v4[1]; vfb[2] = v4[2]; vfb[3] = v4[3];
        vfb[4] = vfb[5] = vfb[6] = vfb[7] = (_Float16)0.f;
        oacc[nd] =
            __builtin_amdgcn_mfma_f32_16x16x32_f16(af, vfb, oacc[nd], 0, 0, 0);
      }
    }
    // rotate prev sets; issue next batch (distance ~4 chunk bodies)
#pragma unroll
    for (int j = 0; j < 4; ++j) pcur[j] = pnext[j];
    if (g < 2) {
#pragma unroll
      for (int j = 0; j < 4; ++j)
        pnext[j] = *(const f32x4*)(prow + ((g + 2) * 4 + j) * 64);
    }
  }

  // Z partials: zsum covers (q=l15, wave's t-slices); reduce lg groups
  zsum += __shfl_xor(zsum, 16, 64);
  zsum += __shfl_xor(zsum, 32, 64);
  if (lg == 0) zb[w][l15] = zsum;

  // O partials -> LDS
#pragma unroll
  for (int nd = 0; nd < 4; ++nd)
#pragma unroll
    for (int i = 0; i < 4; ++i)
      ob4[w][lg * 4 + i][nd * 16 + l15] = oacc[nd][i];

  __syncthreads();   // El + ob4 + zb complete for all waves

  // final O: thread -> q = tid>>4, d run (tid&15)*4
  {
    const int qq = tid >> 4, dd = (tid & 15) * 4;
    const float z = (zb[0][qq] + zb[1][qq]) + (zb[2][qq] + zb[3][qq]);
    const float rzq = 1.0f / z;
    f32x4 o0 = *(const f32x4*)&ob4[0][qq][dd];
    f32x4 o1 = *(const f32x4*)&ob4[1][qq][dd];
    f32x4 o2 = *(const f32x4*)&ob4[2][qq][dd];
    f32x4 o3 = *(const f32x4*)&ob4[3][qq][dd];
    f32x4 o = ((o0 + o1) + (o2 + o3));
    o[0] *= rzq; o[1] *= rzq; o[2] *= rzq; o[3] *= rzq;
    *(f32x4*)(out + ((size_t)hb * L_ + ltile * QB + qq) * (size_t)D_ + dd) = o;
  }

  // att phase: barrier-free normalized streaming from El
  {
    const int row = tid >> 4, tc = tid & 15;
    const float z = (zb[0][row] + zb[1][row]) + (zb[2][row] + zb[3][row]);
    const float rzr = 1.0f / z;
    float* attw =
        att + ((size_t)hb * L_ + ltile * QB + row) * (size_t)T_ + tc * 4;
    const _Float16* ep = &El[row][tc * 4];
#pragma unroll
    for (int j = 0; j < 16; ++j) {
      half4 ev = *(const half4*)(ep + j * 64);
      f32x4 s = {(float)ev[0] * rzr, (float)ev[1] * rzr,
                 (float)ev[2] * rzr, (float)ev[3] * rzr};
      *(f32x4*)(attw + j * 64) = s;
    }
  }
}

// ===========================================================================
// Fallback (r9 kernel, validated): used only if ws_size is too small.
// ===========================================================================
__global__ __launch_bounds__(256, 3) void attn_fused(
    const float* __restrict__ q, const float* __restrict__ kk,
    const float* __restrict__ vv, const float* __restrict__ prev,
    float* __restrict__ out, float* __restrict__ att) {
  __shared__ __align__(16) _Float16 El[QB][1032];
  __shared__ __align__(16) unsigned char KV[18432];
  __shared__ float zb[4][16];

  auto Ks  = (_Float16(*)[72])KV;
  auto Vt  = (_Float16(*)[72])(KV + 9216);
  auto ob4 = (float(*)[16][72])KV;

  const int ltile = blockIdx.x;
  const int hb    = blockIdx.y;
  const int tid = threadIdx.x;
  const int w = tid >> 6, l = tid & 63, l15 = l & 15, lg = l >> 4;
  const int qrow = ltile * QB + l15;

  half8 qb2[2];
  {
    const float* qp = q + ((size_t)hb * L_ + qrow) * D_ + lg * 8;
#pragma unroll
    for (int f = 0; f < 2; ++f)
#pragma unroll
      for (int e = 0; e < 8; ++e) qb2[f][e] = (_Float16)qp[f * 32 + e];
  }

  const float* prow =
      prev + ((size_t)hb * L_ + qrow) * (size_t)T_ + w * 16 + lg * 4;
  const float* kbase = kk + (size_t)hb * T_ * D_;
  const float* vbase = vv + (size_t)hb * T_ * D_;

  const int sr = tid >> 2;
  const int sc = (tid & 3) * 16;
  const int sv_d = (tid & 15) * 4;
  const int sv_t = (tid >> 4) * 4;

  f32x4 kq[2][4], vq[2][4];
  f32x4 pbv[2];
  auto kload = [&](int c, int s) {
    const float* p = kbase + (size_t)(c * 64 + sr) * D_ + sc;
#pragma unroll
    for (int i = 0; i < 4; ++i) kq[s][i] = *(const f32x4*)(p + i * 4);
  };
  auto vload = [&](int c, int s) {
    const float* p = vbase + (size_t)(c * 64 + sv_t) * D_ + sv_d;
#pragma unroll
    for (int j = 0; j < 4; ++j) vq[s][j] = *(const f32x4*)(p + j * D_);
  };
  auto pload = [&](int c, int s) { pbv[s] = *(const f32x4*)(prow + c * 64); };
  auto kwrite = [&](int s) {
    half8 h0, h1;
#pragma unroll
    for (int e = 0; e < 4; ++e) {
      h0[e]     = (_Float16)kq[s][0][e];
      h0[4 + e] = (_Float16)kq[s][1][e];
      h1[e]     = (_Float16)kq[s][2][e];
      h1[4 + e] = (_Float16)kq[s][3][e];
    }
    *(half8*)&Ks[sr][sc] = h0;
    *(half8*)&Ks[sr][sc + 8] = h1;
  };
  auto vwrite = [&](int s) {
#pragma unroll
    for (int dd = 0; dd < 4; ++dd) {
      half2v a, b;
      a[0] = (_Float16)vq[s][0][dd]; a[1] = (_Float16)vq[s][1][dd];
      b[0] = (_Float16)vq[s][2][dd]; b[1] = (_Float16)vq[s][3][dd];
      *(half2v*)&Vt[sv_d + dd][sv_t]     = a;
      *(half2v*)&Vt[sv_d + dd][sv_t + 2] = b;
    }
  };

  kload(0, 0); vload(0, 0); pload(0, 0);
  kwrite(0); vwrite(0);
  kload(1, 1); vload(1, 1); pload(1, 1);

  float zsum = 0.f;
  f32x4 oacc[4];
#pragma unroll
  for (int nd = 0; nd < 4; ++nd) oacc[nd] = (f32x4){0.f, 0.f, 0.f, 0.f};

#pragma unroll 2
  for (int c = 0; c < 16; ++c) {
    BARRIER();
    f32x4 pv = pbv[c & 1];
    if (c < 14) {
      kload(c + 2, c & 1);
      vload(c + 2, c & 1);
      pload(c + 2, c & 1);
    }

    const int trow = w * 16 + l15;
    half8 ka0 = *(const half8*)&Ks[trow][lg * 8];
    half8 ka1 = *(const half8*)&Ks[trow][32 + lg * 8];
    f32x4 acc = {0.f, 0.f, 0.f, 0.f};
    acc = __builtin_amdgcn_mfma_f32_16x16x32_f16(ka0, qb2[0], acc, 0, 0, 0);
    acc = __builtin_amdgcn_mfma_f32_16x16x32_f16(ka1, qb2[1], acc, 0, 0, 0);

    float e0 = __expf(acc[0] * SCALE + pv[0]);
    float e1 = __expf(acc[1] * SCALE + pv[1]);
    float e2 = __expf(acc[2] * SCALE + pv[2]);
    float e3 = __expf(acc[3] * SCALE + pv[3]);
    zsum += (e0 + e1) + (e2 + e3);
    half4 ev;
    ev[0] = (_Float16)e0; ev[1] = (_Float16)e1;
    ev[2] = (_Float16)e2; ev[3] = (_Float16)e3;
    *(half4*)&El[l15][c * 64 + w * 16 + lg * 4] = ev;

    half8 af;
    af[0] = ev[0]; af[1] = ev[1]; af[2] = ev[2]; af[3] = ev[3];
    af[4] = af[5] = af[6] = af[7] = (_Float16)0.f;
#pragma unroll
    for (int nd = 0; nd < 4; ++nd) {
      half4 v4 = *(const half4*)&Vt[nd * 16 + l15][w * 16 + lg * 4];
      half8 vfb;
      vfb[0] = v4[0]; vfb[1] = v4[1]; vfb[2] = v4[2]; vfb[3] = v4[3];
      vfb[4] = vfb[5] = vfb[6] = vfb[7] = (_Float16)0.f;
      oacc[nd] = __builtin_amdgcn_mfma_f32_16x16x32_f16(af, vfb, oacc[nd], 0, 0, 0);
    }

    BARRIER();
    if (c < 15) { kwrite((c + 1) & 1); vwrite((c + 1) & 1); }
  }

  zsum += __shfl_xor(zsum, 16, 64);
  zsum += __shfl_xor(zsum, 32, 64);
  if (lg == 0) zb[w][l15] = zsum;

#pragma unroll
  for (int nd = 0; nd < 4; ++nd)
#pragma unroll
    for (int i = 0; i < 4; ++i)
      ob4[w][lg * 4 + i][nd * 16 + l15] = oacc[nd][i];
  __syncthreads();

  {
    const int qq = tid >> 4, dd = (tid & 15) * 4;
    const float z = (zb[0][qq] + zb[1][qq]) + (zb[2][qq] + zb[3][qq]);
    const float rzq = 1.0f / z;
    f32x4 o0 = *(const f32x4*)&ob4[0][qq][dd];
    f32x4 o1 = *(const f32x4*)&ob4[1][qq][dd];
    f32x4 o2 = *(const f32x4*)&ob4[2][qq][dd];
    f32x4 o3 = *(const f32x4*)&ob4[3][qq][dd];
    f32x4 o = ((o0 + o1) + (o2 + o3));
    o[0] *= rzq; o[1] *= rzq; o[2] *= rzq; o[3] *= rzq;
    *(f32x4*)(out + ((size_t)hb * L_ + ltile * QB + qq) * (size_t)D_ + dd) = o;
  }

  {
    const int row = tid >> 4, tc = tid & 15;
    const float z = (zb[0][row] + zb[1][row]) + (zb[2][row] + zb[3][row]);
    const float rzr = 1.0f / z;
    float* attw =
        att + ((size_t)hb * L_ + ltile * QB + row) * (size_t)T_ + tc * 4;
    const _Float16* ep = &El[row][tc * 4];
#pragma unroll
    for (int j = 0; j < 16; ++j) {
      half4 ev = *(const half4*)(ep + j * 64);
      f32x4 s = {(float)ev[0] * rzr, (float)ev[1] * rzr,
                 (float)ev[2] * rzr, (float)ev[3] * rzr};
      *(f32x4*)(attw + j * 64) = s;
    }
  }
}

extern "C" void kernel_launch(void* const* d_in, const int* in_sizes, int n_in,
                              void* d_out, int out_size, void* d_ws,
                              size_t ws_size, hipStream_t stream) {
  const float* q    = (const float*)d_in[0];  // (H,B,L,D)
  const float* k    = (const float*)d_in[1];  // (H,B,T,D)
  const float* v    = (const float*)d_in[2];  // (H,B,T,D)
  const float* prev = (const float*)d_in[3];  // (H,B,L,T)

  float* out = (float*)d_out;                 // (H,B,L,D)
  float* att = out + (size_t)HB_ * L_ * D_;   // (H,B,L,T)

  const size_t KV_ELEMS = (size_t)HB_ * T_ * D_;      // 4,194,304
  const size_t WS_NEED  = 2 * KV_ELEMS * sizeof(_Float16);  // 16 MB

  if (ws_size >= WS_NEED) {
    _Float16* Kh = (_Float16*)d_ws;
    _Float16* Vh = Kh + KV_ELEMS;
    cvt_k<<<(int)(KV_ELEMS / (256 * 8)), 256, 0, stream>>>(k, Kh);
    cvt_v<<<dim3(T_ / 128, HB_), 256, 0, stream>>>(v, Vh);
    attn_stream<<<dim3(L_ / QB, HB_), 256, 0, stream>>>(q, Kh, Vh, prev, out,
                                                        att);
  } else {
    attn_fused<<<dim3(L_ / QB, HB_), 256, 0, stream>>>(q, k, v, prev, out, att);
  }
}